// Round 4
// baseline (810.165 us; speedup 1.0000x reference)
//
#include <hip/hip_runtime.h>
#include <hip/hip_bf16.h>
#include <math.h>

#define EMB 128
#define OUT 256
#define RAD 6
#define NDL 3
#define NTGT 12
#define MT 32          // nodes per chain block
#define S 264          // LDS activation stride (bf16 elems)
#define GBLK 1536      // gather grid blocks (6 blocks/CU at __launch_bounds__(256,6))

typedef __attribute__((ext_vector_type(8))) short short8;
typedef __attribute__((ext_vector_type(4))) float floatx4;

__device__ inline short f2bf(float x) {
    __hip_bfloat16 h = __float2bfloat16(x);
    return *reinterpret_cast<short*>(&h);
}

// ---------------- CSR build ----------------

__global__ void hist_kernel(const int* __restrict__ src, int* __restrict__ counts, int E) {
    int i = blockIdx.x * blockDim.x + threadIdx.x;
    if (i < E) atomicAdd(&counts[src[i]], 1);
}

__global__ void scan_kernel(const int* __restrict__ counts, int* __restrict__ offs,
                            int* __restrict__ cursor, int N) {
    __shared__ int sums[1024];
    int tid = threadIdx.x;
    int chunk = (N + 1023) / 1024;
    int beg = tid * chunk;
    int end = min(beg + chunk, N);
    int s = 0;
    for (int i = beg; i < end; i++) s += counts[i];
    int mysum = s;
    sums[tid] = s;
    __syncthreads();
    for (int off = 1; off < 1024; off <<= 1) {
        int add = (tid >= off) ? sums[tid - off] : 0;
        __syncthreads();
        sums[tid] += add;
        __syncthreads();
    }
    int prefix = sums[tid] - mysum;
    for (int i = beg; i < end; i++) {
        int c = counts[i];
        offs[i] = prefix;
        cursor[i] = prefix;
        prefix += c;
    }
    if (tid == 0) offs[N] = sums[1023];
}

__global__ void scatter_kernel(const int* __restrict__ src, int* __restrict__ cursor,
                               int* __restrict__ eids, int* __restrict__ pos2node, int E) {
    int i = blockIdx.x * blockDim.x + threadIdx.x;
    if (i < E) {
        int s = src[i];
        int pos = atomicAdd(&cursor[s], 1);
        eids[pos] = i;
        pos2node[pos] = s;
    }
}

// ---------------- weight prep: bf16 + transpose ----------------

__global__ void prep_kernel(const float* __restrict__ w_up, const float* __restrict__ w_dense,
                            const float* __restrict__ w_final,
                            short* __restrict__ w_upT, short* __restrict__ w_dT,
                            short* __restrict__ w_fT) {
    const int T1 = OUT * EMB;
    const int T2 = NDL * OUT * OUT;
    const int T3 = 16 * OUT;
    int total = T1 + T2 + T3;
    for (int i = blockIdx.x * blockDim.x + threadIdx.x; i < total; i += gridDim.x * blockDim.x) {
        if (i < T1) {
            int n = i >> 7, k = i & 127;
            w_upT[i] = f2bf(w_up[k * OUT + n]);
        } else if (i < T1 + T2) {
            int j = i - T1;
            int l = j >> 16, o = (j >> 8) & 255, k = j & 255;
            w_dT[j] = f2bf(w_dense[(l << 16) + (k << 8) + o]);
        } else {
            int j = i - T1 - T2;
            int t = j >> 8, k = j & 255;
            w_fT[j] = (t < NTGT) ? f2bf(w_final[k * NTGT + t]) : (short)0;
        }
    }
}

// ---------------- edge-major gather over CSR stream ----------------
// Each wave owns a contiguous chunk of CSR positions. Half-waves (32 lanes) take
// alternating positions; lane holds 4 columns. 2-deep eid prefetch + 1-deep data
// prefetch keeps >=2 m-row loads in flight per wave. Node-boundary flush via
// atomicAdd into f32 t0 (zero-initialized).

__global__ __launch_bounds__(256, 6) void gather_kernel(
    const float* __restrict__ m, const float* __restrict__ rbf,
    const float* __restrict__ w_rbf,
    const int* __restrict__ eids, const int* __restrict__ pos2node,
    float* __restrict__ t0, int E) {

    int tid = threadIdx.x;
    int lane = tid & 63;
    int grp = lane >> 5;       // 0/1 within wave
    int c = lane & 31;         // column group -> cols 4c..4c+3
    int gwave = blockIdx.x * 4 + (tid >> 6);
    int nW = gridDim.x * 4;
    int chunk = (E + nW - 1) / nW;
    int p0 = gwave * chunk;
    int p1 = min(p0 + chunk, E);

    float4 wq[RAD];
#pragma unroll
    for (int r = 0; r < RAD; r++) wq[r] = *(const float4*)&w_rbf[r * EMB + 4 * c];

    float ax = 0.f, ay = 0.f, az = 0.f, aw = 0.f;
    int prev = -1;

    int p = p0 + grp;
    if (p < p1) {
        int eidA = eids[p];
        int nodeA = pos2node[p];
        int pB = min(p + 2, E - 1);
        int eidB = eids[pB];
        int nodeB = pos2node[pB];
        float4 mv = *(const float4*)&m[(size_t)eidA * EMB + 4 * c];
        const float* rr = &rbf[(size_t)eidA * RAD];
        float2 r0 = *(const float2*)&rr[0];
        float2 r1 = *(const float2*)&rr[2];
        float2 r2 = *(const float2*)&rr[4];

        for (; p < p1; p += 2) {
            // prefetch: next-next eid/node, next data
            int pC = min(p + 4, E - 1);
            int eidC = eids[pC];
            int nodeC = pos2node[pC];
            float4 mvB = *(const float4*)&m[(size_t)eidB * EMB + 4 * c];
            const float* rrB = &rbf[(size_t)eidB * RAD];
            float2 s0 = *(const float2*)&rrB[0];
            float2 s1 = *(const float2*)&rrB[2];
            float2 s2 = *(const float2*)&rrB[4];

            // node boundary flush (group-uniform branch)
            if (nodeA != prev) {
                if (prev >= 0) {
                    float* dst = &t0[(size_t)prev * EMB + 4 * c];
                    atomicAdd(&dst[0], ax); atomicAdd(&dst[1], ay);
                    atomicAdd(&dst[2], az); atomicAdd(&dst[3], aw);
                }
                ax = ay = az = aw = 0.f;
                prev = nodeA;
            }

            // compute with current (A) data
            float cx = wq[0].x*r0.x + wq[1].x*r0.y + wq[2].x*r1.x + wq[3].x*r1.y + wq[4].x*r2.x + wq[5].x*r2.y;
            float cy = wq[0].y*r0.x + wq[1].y*r0.y + wq[2].y*r1.x + wq[3].y*r1.y + wq[4].y*r2.x + wq[5].y*r2.y;
            float cz = wq[0].z*r0.x + wq[1].z*r0.y + wq[2].z*r1.x + wq[3].z*r1.y + wq[4].z*r2.x + wq[5].z*r2.y;
            float cw = wq[0].w*r0.x + wq[1].w*r0.y + wq[2].w*r1.x + wq[3].w*r1.y + wq[4].w*r2.x + wq[5].w*r2.y;
            ax += mv.x * cx; ay += mv.y * cy; az += mv.z * cz; aw += mv.w * cw;

            // rotate pipeline
            mv = mvB; r0 = s0; r1 = s1; r2 = s2;
            nodeA = nodeB; nodeB = nodeC; eidB = eidC;
        }
        if (prev >= 0) {
            float* dst = &t0[(size_t)prev * EMB + 4 * c];
            atomicAdd(&dst[0], ax); atomicAdd(&dst[1], ay);
            atomicAdd(&dst[2], az); atomicAdd(&dst[3], aw);
        }
    }
}

// ---------------- node MLP chain via MFMA + per-graph reduce ----------------

__global__ __launch_bounds__(256) void chain_kernel(
    const float* __restrict__ t0,
    const short* __restrict__ w_upT, const short* __restrict__ w_dT,
    const float* __restrict__ b_dense, const short* __restrict__ w_fT,
    const int* __restrict__ node2graph, float* __restrict__ out, int N) {

    __shared__ short sA[2][MT * S];

    int tid = threadIdx.x;
    int n0 = blockIdx.x * MT;
    int wave = tid >> 6, lane = tid & 63;
    int lo = lane & 15;
    int quad = lane >> 4;
    int kq = quad * 8;
    int wcol = wave * 64;

    // stage t0 tile: f32 -> bf16
    {
        int r = tid >> 3;
        int ccol = (tid & 7) * 16;
        short vals[16];
        if (n0 + r < N) {
            const float* src = &t0[(size_t)(n0 + r) * EMB + ccol];
#pragma unroll
            for (int j = 0; j < 16; j += 4) {
                float4 f = *(const float4*)&src[j];
                vals[j + 0] = f2bf(f.x); vals[j + 1] = f2bf(f.y);
                vals[j + 2] = f2bf(f.z); vals[j + 3] = f2bf(f.w);
            }
        } else {
#pragma unroll
            for (int j = 0; j < 16; j++) vals[j] = 0;
        }
        *(uint4*)&sA[0][r * S + ccol] = *(uint4*)&vals[0];
        *(uint4*)&sA[0][r * S + ccol + 8] = *(uint4*)&vals[8];
    }
    __syncthreads();

    auto layer = [&](int cur, int K, const short* __restrict__ Bt,
                     const float* __restrict__ bias, bool act) {
        floatx4 acc[2][4];
#pragma unroll
        for (int mt = 0; mt < 2; mt++)
#pragma unroll
            for (int nt = 0; nt < 4; nt++)
                acc[mt][nt] = floatx4{0.f, 0.f, 0.f, 0.f};

        for (int kc = 0; kc < K; kc += 32) {
            short8 a0 = *(const short8*)&sA[cur][(lo) * S + kc + kq];
            short8 a1 = *(const short8*)&sA[cur][(16 + lo) * S + kc + kq];
#pragma unroll
            for (int nt = 0; nt < 4; nt++) {
                int n = wcol + nt * 16 + lo;
                short8 b = *(const short8*)&Bt[(size_t)n * K + kc + kq];
                acc[0][nt] = __builtin_amdgcn_mfma_f32_16x16x32_bf16(a0, b, acc[0][nt], 0, 0, 0);
                acc[1][nt] = __builtin_amdgcn_mfma_f32_16x16x32_bf16(a1, b, acc[1][nt], 0, 0, 0);
            }
        }

        float bv[4];
#pragma unroll
        for (int nt = 0; nt < 4; nt++) bv[nt] = bias ? bias[wcol + nt * 16 + lo] : 0.f;

        short* dst = sA[cur ^ 1];
#pragma unroll
        for (int mt = 0; mt < 2; mt++)
#pragma unroll
            for (int nt = 0; nt < 4; nt++) {
                int n = wcol + nt * 16 + lo;
#pragma unroll
                for (int i = 0; i < 4; i++) {
                    int mrow = mt * 16 + quad * 4 + i;
                    float x = acc[mt][nt][i] + bv[nt];
                    if (act) x = x / (1.f + __expf(-x));
                    dst[mrow * S + n] = f2bf(x);
                }
            }
        __syncthreads();
    };

    layer(0, EMB, w_upT, nullptr, false);
    layer(1, OUT, w_dT + 0 * OUT * OUT, b_dense + 0 * OUT, true);
    layer(0, OUT, w_dT + 1 * OUT * OUT, b_dense + 1 * OUT, true);
    layer(1, OUT, w_dT + 2 * OUT * OUT, b_dense + 2 * OUT, true);

    if (wave == 0) {
        floatx4 facc[2];
        facc[0] = floatx4{0.f, 0.f, 0.f, 0.f};
        facc[1] = floatx4{0.f, 0.f, 0.f, 0.f};
        for (int kc = 0; kc < OUT; kc += 32) {
            short8 a0 = *(const short8*)&sA[0][(lo) * S + kc + kq];
            short8 a1 = *(const short8*)&sA[0][(16 + lo) * S + kc + kq];
            short8 b = *(const short8*)&w_fT[lo * OUT + kc + kq];
            facc[0] = __builtin_amdgcn_mfma_f32_16x16x32_bf16(a0, b, facc[0], 0, 0, 0);
            facc[1] = __builtin_amdgcn_mfma_f32_16x16x32_bf16(a1, b, facc[1], 0, 0, 0);
        }
        if (lo < NTGT) {
#pragma unroll
            for (int mt = 0; mt < 2; mt++)
#pragma unroll
                for (int i = 0; i < 4; i++) {
                    int node = n0 + mt * 16 + quad * 4 + i;
                    if (node < N)
                        atomicAdd(&out[node2graph[node] * NTGT + lo], facc[mt][i]);
                }
        }
    }
}

// ---------------- launch ----------------

extern "C" void kernel_launch(void* const* d_in, const int* in_sizes, int n_in,
                              void* d_out, int out_size, void* d_ws, size_t ws_size,
                              hipStream_t stream) {
    const float* m        = (const float*)d_in[0];
    const float* rbf      = (const float*)d_in[1];
    const int*   edge_src = (const int*)d_in[2];
    const int*   node2g   = (const int*)d_in[3];
    const float* w_rbf    = (const float*)d_in[4];
    const float* w_up     = (const float*)d_in[5];
    const float* w_dense  = (const float*)d_in[6];
    const float* b_dense  = (const float*)d_in[7];
    const float* w_final  = (const float*)d_in[8];

    int E = in_sizes[2];
    int N = in_sizes[3];
    float* out = (float*)d_out;

    char* p = (char*)d_ws;
    auto alloc = [&](size_t bytes) {
        char* r = p;
        p += (bytes + 255) & ~(size_t)255;
        return r;
    };
    int*   counts   = (int*)alloc((size_t)N * 4);
    int*   offs     = (int*)alloc((size_t)(N + 1) * 4);
    int*   cursor   = (int*)alloc((size_t)N * 4);
    int*   eids     = (int*)alloc((size_t)E * 4);
    int*   pos2node = (int*)alloc((size_t)E * 4);
    float* t0       = (float*)alloc((size_t)N * EMB * 4);
    short* w_upT    = (short*)alloc((size_t)OUT * EMB * 2);
    short* w_dT     = (short*)alloc((size_t)NDL * OUT * OUT * 2);
    short* w_fT     = (short*)alloc((size_t)16 * OUT * 2);

    hipMemsetAsync(counts, 0, (size_t)N * 4, stream);
    hipMemsetAsync(t0, 0, (size_t)N * EMB * 4, stream);
    hipMemsetAsync(d_out, 0, (size_t)out_size * 4, stream);

    prep_kernel<<<512, 256, 0, stream>>>(w_up, w_dense, w_final, w_upT, w_dT, w_fT);
    hist_kernel<<<(E + 255) / 256, 256, 0, stream>>>(edge_src, counts, E);
    scan_kernel<<<1, 1024, 0, stream>>>(counts, offs, cursor, N);
    scatter_kernel<<<(E + 255) / 256, 256, 0, stream>>>(edge_src, cursor, eids, pos2node, E);
    gather_kernel<<<GBLK, 256, 0, stream>>>(m, rbf, w_rbf, eids, pos2node, t0, E);
    chain_kernel<<<(N + MT - 1) / MT, 256, 0, stream>>>(t0, w_upT, w_dT, b_dense,
                                                        w_fT, node2g, out, N);
}